// Round 1
// baseline (385.904 us; speedup 1.0000x reference)
//
#include <hip/hip_runtime.h>
#include <type_traits>

// StructuralLoss: windowed ZNCC loss, sigma=4 -> w=2 (4x4 box windows).
// Fully local: out pixel (i,j) depends on raw 7x7 neighborhood.
// Strategy: register-streaming, no LDS staging. Each thread owns 4 output
// columns, streams RY rows. Rings (raw rows, H product-sums) kept in
// registers with compile-time phase via template<int K> step.
//
// R1: RY 32 -> 16. Grid 512 -> 1024 blocks = 4 blocks/CU = 4 waves/SIMD
// (VGPR=108 fits 4 waves under the 128-VGPR occupancy cliff). The per-step
// load->use distance is tiny, so exposed L2/L3 latency must be covered by
// TLP; 2 waves/SIMD gave only 48.7% VALUBusy. Atomics reduced to 1/block.

#define HH 4096
#define WW 4096
constexpr int RY = 16;            // output rows per thread
constexpr float EPf = 1e-20f;

__device__ __forceinline__ float4 zero4() { return make_float4(0.f, 0.f, 0.f, 0.f); }

struct ThreadState {
    // raw row rings: [slot][12 cols]  cols j0-4 .. j0+7
    float A[4][12];
    float B[4][12];
    // H rings: [slot][4 output cols]
    float Hii[4][4], Hjj[4][4], Hij[4][4];
    float cmask[7];               // c-column validity (cols j0-1 .. j0+5)
    float acc;
};

template <int SLOT>
__device__ __forceinline__ void load_row(ThreadState& st,
                                         const float* __restrict__ i1,
                                         const float* __restrict__ i2,
                                         int t, int j0, bool okL, bool okR) {
    float4 a0, a1, a2, b0, b1, b2;
    if (t >= 0 && t < HH) {                       // wave-uniform branch
        const float* p1 = i1 + (long)t * WW + j0;
        const float* p2 = i2 + (long)t * WW + j0;
        a0 = okL ? *(const float4*)(p1 - 4) : zero4();
        a1 = *(const float4*)(p1);
        a2 = okR ? *(const float4*)(p1 + 4) : zero4();
        b0 = okL ? *(const float4*)(p2 - 4) : zero4();
        b1 = *(const float4*)(p2);
        b2 = okR ? *(const float4*)(p2 + 4) : zero4();
    } else {
        a0 = a1 = a2 = b0 = b1 = b2 = zero4();
    }
    st.A[SLOT][0] = a0.x; st.A[SLOT][1] = a0.y; st.A[SLOT][2]  = a0.z; st.A[SLOT][3]  = a0.w;
    st.A[SLOT][4] = a1.x; st.A[SLOT][5] = a1.y; st.A[SLOT][6]  = a1.z; st.A[SLOT][7]  = a1.w;
    st.A[SLOT][8] = a2.x; st.A[SLOT][9] = a2.y; st.A[SLOT][10] = a2.z; st.A[SLOT][11] = a2.w;
    st.B[SLOT][0] = b0.x; st.B[SLOT][1] = b0.y; st.B[SLOT][2]  = b0.z; st.B[SLOT][3]  = b0.w;
    st.B[SLOT][4] = b1.x; st.B[SLOT][5] = b1.y; st.B[SLOT][6]  = b1.z; st.B[SLOT][7]  = b1.w;
    st.B[SLOT][8] = b2.x; st.B[SLOT][9] = b2.y; st.B[SLOT][10] = b2.z; st.B[SLOT][11] = b2.w;
}

template <int K>
__device__ __forceinline__ void step(ThreadState& st,
                                     const float* __restrict__ i1,
                                     const float* __restrict__ i2,
                                     int rrb, int y0, int j0, bool okL, bool okR) {
    const int rr = rrb + K;        // iteration index 0..(RY+3)
    const int r  = y0 - 1 + rr;    // c-row being produced this iteration
    // load raw row t = r+2 into slot rr&3 == K
    load_row<K>(st, i1, i2, r + 2, j0, okL, okR);

    // vertical 4-sums over the ring (rows r-1..r+2), all 12 cols
    float vs1[12], vs2[12];
#pragma unroll
    for (int m = 0; m < 12; ++m) {
        vs1[m] = st.A[0][m] + st.A[1][m] + st.A[2][m] + st.A[3][m];
        vs2[m] = st.B[0][m] + st.B[1][m] + st.B[2][m] + st.B[3][m];
    }

    constexpr int CS = (K + 2) & 3;  // slot holding raw row r (center)
    const float rmask = (r >= 0 && r < HH) ? 1.f : 0.f;

    // centered values at 7 c-columns (global col j0-1+m)
    float c1[7], c2[7];
#pragma unroll
    for (int m = 0; m < 7; ++m) {
        float mu1 = (vs1[m + 2] + vs1[m + 3] + vs1[m + 4] + vs1[m + 5]) * 0.0625f;
        float mu2 = (vs2[m + 2] + vs2[m + 3] + vs2[m + 4] + vs2[m + 5]) * 0.0625f;
        float msk = rmask * st.cmask[m];
        c1[m] = (st.A[CS][m + 3] - mu1) * msk;
        c2[m] = (st.B[CS][m + 3] - mu2) * msk;
    }

    // horizontal 4-sums of products for the 4 output columns -> H ring slot K
#pragma unroll
    for (int q = 0; q < 4; ++q) {
        float hii = 0.f, hjj = 0.f, hij = 0.f;
#pragma unroll
        for (int s = 0; s < 4; ++s) {
            float a = c1[q + s], b = c2[q + s];
            hii += a * a;
            hjj += b * b;
            hij += a * b;
        }
        st.Hii[K][q] = hii; st.Hjj[K][q] = hjj; st.Hij[K][q] = hij;
    }

    // emit output row i = r-2 once H ring holds c-rows i-1..i+2
    if (rr >= 3 && rr <= RY + 2) {     // wave-uniform
#pragma unroll
        for (int q = 0; q < 4; ++q) {
            float sii = st.Hii[0][q] + st.Hii[1][q] + st.Hii[2][q] + st.Hii[3][q];
            float sjj = st.Hjj[0][q] + st.Hjj[1][q] + st.Hjj[2][q] + st.Hjj[3][q];
            float sij = st.Hij[0][q] + st.Hij[1][q] + st.Hij[2][q] + st.Hij[3][q];
            sii = fmaxf(sii, EPf);
            sjj = fmaxf(sjj, EPf);
            float L = sij / (sqrtf(sii * sjj) + EPf);
            L = fmaxf(L, -1.f);
            st.acc += 1.f - L;
        }
    }
}

__global__ __launch_bounds__(256, 4) void xcorr_loss_kernel(
    const float* __restrict__ img1, const float* __restrict__ img2,
    double* __restrict__ ws) {
    const int tcol = blockIdx.x * blockDim.x + threadIdx.x;  // thread col-group
    const int j0   = tcol * 4;
    const int y0   = blockIdx.y * RY;

    ThreadState st;
    st.acc = 0.f;
#pragma unroll
    for (int m = 0; m < 7; ++m) {
        int cc = j0 - 1 + m;
        st.cmask[m] = (cc >= 0 && cc < WW) ? 1.f : 0.f;
    }
    const bool okL = (j0 - 4) >= 0;       // left float4 block fully in range
    const bool okR = (j0 + 7) < WW;       // right float4 block fully in range

    // prime raw ring with rows y0-2, y0-1, y0 (slots 1,2,3)
    load_row<1>(st, img1, img2, y0 - 2, j0, okL, okR);
    load_row<2>(st, img1, img2, y0 - 1, j0, okL, okR);
    load_row<3>(st, img1, img2, y0,     j0, okL, okR);

    // RY+3 = 19 iterations needed, padded to 20 (multiple of 4); last is a
    // no-emit dummy.
    for (int o = 0; o < (RY + 3 + 3) / 4; ++o) {
        const int rrb = o * 4;
        step<0>(st, img1, img2, rrb, y0, j0, okL, okR);
        step<1>(st, img1, img2, rrb, y0, j0, okL, okR);
        step<2>(st, img1, img2, rrb, y0, j0, okL, okR);
        step<3>(st, img1, img2, rrb, y0, j0, okL, okR);
    }

    // wave (64-lane) reduction -> LDS -> one double atomic per block
    float wsum = st.acc;
#pragma unroll
    for (int off = 32; off > 0; off >>= 1)
        wsum += __shfl_down(wsum, off, 64);

    __shared__ float wpart[4];
    const int wid = threadIdx.x >> 6;
    if ((threadIdx.x & 63) == 0) wpart[wid] = wsum;
    __syncthreads();
    if (threadIdx.x == 0) {
        float bsum = wpart[0] + wpart[1] + wpart[2] + wpart[3];
        atomicAdd(ws, (double)bsum);
    }
}

__global__ void finalize_kernel(const double* __restrict__ ws, float* __restrict__ out) {
    double mean = ws[0] / ((double)HH * (double)WW);
    out[0] = (float)mean;
    out[1] = (float)mean;
}

extern "C" void kernel_launch(void* const* d_in, const int* in_sizes, int n_in,
                              void* d_out, int out_size, void* d_ws, size_t ws_size,
                              hipStream_t stream) {
    const float* img1 = (const float*)d_in[0];  // outputs
    const float* img2 = (const float*)d_in[1];  // labels
    double* ws = (double*)d_ws;

    hipMemsetAsync(d_ws, 0, sizeof(double), stream);

    dim3 grid(WW / (256 * 4), HH / RY);   // (4, 256) = 1024 blocks
    xcorr_loss_kernel<<<grid, dim3(256), 0, stream>>>(img1, img2, ws);
    finalize_kernel<<<1, 1, 0, stream>>>(ws, (float*)d_out);
}

// Round 2
// 185.801 us; speedup vs baseline: 2.0770x; 2.0770x over previous
//
#include <hip/hip_runtime.h>
#include <type_traits>

// StructuralLoss: windowed ZNCC loss, sigma=4 -> w=2 (4x4 box windows).
// Fully local: out pixel (i,j) depends on raw 7x7 neighborhood.
// Strategy: register-streaming, no LDS staging. Each thread owns 4 output
// columns, streams RY rows. Rings (raw rows, H product-sums) kept in
// registers with compile-time phase via template<int K> step.
//
// R1: RY 32 -> 16, grid 1024 blocks. Occupancy 18.7 -> 43% (validated).
// R1 FAIL: __launch_bounds__(256,4) capped VGPR at 64 -> ThreadState spilled
//   to scratch (WRITE_SIZE 64B -> 490MB, dur 285us). Lesson: never pin the
//   allocator below the state size; VGPR=108 already allows 4 waves/SIMD
//   (floor(512/108)=4) with no hint.
// R2: plain __launch_bounds__(256). Keep RY=16 grid + block-level atomic.

#define HH 4096
#define WW 4096
constexpr int RY = 16;            // output rows per thread
constexpr float EPf = 1e-20f;

__device__ __forceinline__ float4 zero4() { return make_float4(0.f, 0.f, 0.f, 0.f); }

struct ThreadState {
    // raw row rings: [slot][12 cols]  cols j0-4 .. j0+7
    float A[4][12];
    float B[4][12];
    // H rings: [slot][4 output cols]
    float Hii[4][4], Hjj[4][4], Hij[4][4];
    float cmask[7];               // c-column validity (cols j0-1 .. j0+5)
    float acc;
};

template <int SLOT>
__device__ __forceinline__ void load_row(ThreadState& st,
                                         const float* __restrict__ i1,
                                         const float* __restrict__ i2,
                                         int t, int j0, bool okL, bool okR) {
    float4 a0, a1, a2, b0, b1, b2;
    if (t >= 0 && t < HH) {                       // wave-uniform branch
        const float* p1 = i1 + (long)t * WW + j0;
        const float* p2 = i2 + (long)t * WW + j0;
        a0 = okL ? *(const float4*)(p1 - 4) : zero4();
        a1 = *(const float4*)(p1);
        a2 = okR ? *(const float4*)(p1 + 4) : zero4();
        b0 = okL ? *(const float4*)(p2 - 4) : zero4();
        b1 = *(const float4*)(p2);
        b2 = okR ? *(const float4*)(p2 + 4) : zero4();
    } else {
        a0 = a1 = a2 = b0 = b1 = b2 = zero4();
    }
    st.A[SLOT][0] = a0.x; st.A[SLOT][1] = a0.y; st.A[SLOT][2]  = a0.z; st.A[SLOT][3]  = a0.w;
    st.A[SLOT][4] = a1.x; st.A[SLOT][5] = a1.y; st.A[SLOT][6]  = a1.z; st.A[SLOT][7]  = a1.w;
    st.A[SLOT][8] = a2.x; st.A[SLOT][9] = a2.y; st.A[SLOT][10] = a2.z; st.A[SLOT][11] = a2.w;
    st.B[SLOT][0] = b0.x; st.B[SLOT][1] = b0.y; st.B[SLOT][2]  = b0.z; st.B[SLOT][3]  = b0.w;
    st.B[SLOT][4] = b1.x; st.B[SLOT][5] = b1.y; st.B[SLOT][6]  = b1.z; st.B[SLOT][7]  = b1.w;
    st.B[SLOT][8] = b2.x; st.B[SLOT][9] = b2.y; st.B[SLOT][10] = b2.z; st.B[SLOT][11] = b2.w;
}

template <int K>
__device__ __forceinline__ void step(ThreadState& st,
                                     const float* __restrict__ i1,
                                     const float* __restrict__ i2,
                                     int rrb, int y0, int j0, bool okL, bool okR) {
    const int rr = rrb + K;        // iteration index 0..(RY+3)
    const int r  = y0 - 1 + rr;    // c-row being produced this iteration
    // load raw row t = r+2 into slot rr&3 == K
    load_row<K>(st, i1, i2, r + 2, j0, okL, okR);

    // vertical 4-sums over the ring (rows r-1..r+2), all 12 cols
    float vs1[12], vs2[12];
#pragma unroll
    for (int m = 0; m < 12; ++m) {
        vs1[m] = st.A[0][m] + st.A[1][m] + st.A[2][m] + st.A[3][m];
        vs2[m] = st.B[0][m] + st.B[1][m] + st.B[2][m] + st.B[3][m];
    }

    constexpr int CS = (K + 2) & 3;  // slot holding raw row r (center)
    const float rmask = (r >= 0 && r < HH) ? 1.f : 0.f;

    // centered values at 7 c-columns (global col j0-1+m)
    float c1[7], c2[7];
#pragma unroll
    for (int m = 0; m < 7; ++m) {
        float mu1 = (vs1[m + 2] + vs1[m + 3] + vs1[m + 4] + vs1[m + 5]) * 0.0625f;
        float mu2 = (vs2[m + 2] + vs2[m + 3] + vs2[m + 4] + vs2[m + 5]) * 0.0625f;
        float msk = rmask * st.cmask[m];
        c1[m] = (st.A[CS][m + 3] - mu1) * msk;
        c2[m] = (st.B[CS][m + 3] - mu2) * msk;
    }

    // horizontal 4-sums of products for the 4 output columns -> H ring slot K
#pragma unroll
    for (int q = 0; q < 4; ++q) {
        float hii = 0.f, hjj = 0.f, hij = 0.f;
#pragma unroll
        for (int s = 0; s < 4; ++s) {
            float a = c1[q + s], b = c2[q + s];
            hii += a * a;
            hjj += b * b;
            hij += a * b;
        }
        st.Hii[K][q] = hii; st.Hjj[K][q] = hjj; st.Hij[K][q] = hij;
    }

    // emit output row i = r-2 once H ring holds c-rows i-1..i+2
    if (rr >= 3 && rr <= RY + 2) {     // wave-uniform
#pragma unroll
        for (int q = 0; q < 4; ++q) {
            float sii = st.Hii[0][q] + st.Hii[1][q] + st.Hii[2][q] + st.Hii[3][q];
            float sjj = st.Hjj[0][q] + st.Hjj[1][q] + st.Hjj[2][q] + st.Hjj[3][q];
            float sij = st.Hij[0][q] + st.Hij[1][q] + st.Hij[2][q] + st.Hij[3][q];
            sii = fmaxf(sii, EPf);
            sjj = fmaxf(sjj, EPf);
            float L = sij / (sqrtf(sii * sjj) + EPf);
            L = fmaxf(L, -1.f);
            st.acc += 1.f - L;
        }
    }
}

__global__ __launch_bounds__(256) void xcorr_loss_kernel(
    const float* __restrict__ img1, const float* __restrict__ img2,
    double* __restrict__ ws) {
    const int tcol = blockIdx.x * blockDim.x + threadIdx.x;  // thread col-group
    const int j0   = tcol * 4;
    const int y0   = blockIdx.y * RY;

    ThreadState st;
    st.acc = 0.f;
#pragma unroll
    for (int m = 0; m < 7; ++m) {
        int cc = j0 - 1 + m;
        st.cmask[m] = (cc >= 0 && cc < WW) ? 1.f : 0.f;
    }
    const bool okL = (j0 - 4) >= 0;       // left float4 block fully in range
    const bool okR = (j0 + 7) < WW;       // right float4 block fully in range

    // prime raw ring with rows y0-2, y0-1, y0 (slots 1,2,3)
    load_row<1>(st, img1, img2, y0 - 2, j0, okL, okR);
    load_row<2>(st, img1, img2, y0 - 1, j0, okL, okR);
    load_row<3>(st, img1, img2, y0,     j0, okL, okR);

    // RY+3 = 19 iterations needed, padded to 20 (multiple of 4); last is a
    // no-emit dummy.
    for (int o = 0; o < (RY + 3 + 3) / 4; ++o) {
        const int rrb = o * 4;
        step<0>(st, img1, img2, rrb, y0, j0, okL, okR);
        step<1>(st, img1, img2, rrb, y0, j0, okL, okR);
        step<2>(st, img1, img2, rrb, y0, j0, okL, okR);
        step<3>(st, img1, img2, rrb, y0, j0, okL, okR);
    }

    // wave (64-lane) reduction -> LDS -> one double atomic per block
    float wsum = st.acc;
#pragma unroll
    for (int off = 32; off > 0; off >>= 1)
        wsum += __shfl_down(wsum, off, 64);

    __shared__ float wpart[4];
    const int wid = threadIdx.x >> 6;
    if ((threadIdx.x & 63) == 0) wpart[wid] = wsum;
    __syncthreads();
    if (threadIdx.x == 0) {
        float bsum = wpart[0] + wpart[1] + wpart[2] + wpart[3];
        atomicAdd(ws, (double)bsum);
    }
}

__global__ void finalize_kernel(const double* __restrict__ ws, float* __restrict__ out) {
    double mean = ws[0] / ((double)HH * (double)WW);
    out[0] = (float)mean;
    out[1] = (float)mean;
}

extern "C" void kernel_launch(void* const* d_in, const int* in_sizes, int n_in,
                              void* d_out, int out_size, void* d_ws, size_t ws_size,
                              hipStream_t stream) {
    const float* img1 = (const float*)d_in[0];  // outputs
    const float* img2 = (const float*)d_in[1];  // labels
    double* ws = (double*)d_ws;

    hipMemsetAsync(d_ws, 0, sizeof(double), stream);

    dim3 grid(WW / (256 * 4), HH / RY);   // (4, 256) = 1024 blocks
    xcorr_loss_kernel<<<grid, dim3(256), 0, stream>>>(img1, img2, ws);
    finalize_kernel<<<1, 1, 0, stream>>>(ws, (float*)d_out);
}